// Round 1
// baseline (5954.366 us; speedup 1.0000x reference)
//
#include <hip/hip_runtime.h>
#include <math.h>

#define NN    100000
#define NE    1600000
#define FEAT  128
#define GQ    4
#define NL    3
#define NGR   64
#define NCLS  10
#define KSPL  512   /* FEAT*GQ */

__device__ __forceinline__ float fsilu(float x){ return x / (1.f + __expf(-x)); }

__global__ __launch_bounds__(256) void k_fill(float* __restrict__ p, int n, float v){
  int i = blockIdx.x*256 + threadIdx.x;
  if (i < n) p[i] = v;
}

__global__ __launch_bounds__(256) void k_deg(const int* __restrict__ dst, float* __restrict__ deg, int ne){
  int e = blockIdx.x*256 + threadIdx.x;
  if (e < ne) atomicAdd(&deg[dst[e]], 1.f);
}

__global__ __launch_bounds__(256) void k_dinv(float* __restrict__ deg, int n){
  int i = blockIdx.x*256 + threadIdx.x;
  if (i < n) deg[i] = rsqrtf(deg[i]);   // deg >= 1 always (self-loop)
}

// FastKAN transform for 4 nodes per block, 128 threads (one per output chan).
__global__ __launch_bounds__(128) void k_fkan(
    const float* __restrict__ xin, float* __restrict__ h,
    const float* __restrict__ ln_s, const float* __restrict__ ln_b,
    const float* __restrict__ sW, const float* __restrict__ sb,
    const float* __restrict__ bW, const float* __restrict__ bb,
    int n_nodes)
{
  __shared__ float cb[4][KSPL + FEAT];   // per node: 512 rbf basis + 128 silu(x)
  __shared__ float wred[2][2];
  const int tid  = threadIdx.x;
  const int lane = tid & 63, wave = tid >> 6;
  const int node0 = blockIdx.x * 4;
  const float lns = ln_s[tid], lnb = ln_b[tid];

  float xv_keep[4];
  for (int nn = 0; nn < 4; ++nn) {
    const int node = node0 + nn;
    float xv = (node < n_nodes) ? xin[(size_t)node*FEAT + tid] : 0.f;
    xv_keep[nn] = xv;
    float s1 = xv, s2 = xv*xv;
    #pragma unroll
    for (int off = 32; off; off >>= 1) { s1 += __shfl_down(s1, off); s2 += __shfl_down(s2, off); }
    if (lane == 0) { wred[wave][0] = s1; wred[wave][1] = s2; }
    __syncthreads();
    const float m   = (wred[0][0] + wred[1][0]) * (1.f/FEAT);
    const float var = (wred[0][1] + wred[1][1]) * (1.f/FEAT) - m*m;
    const float rs  = rsqrtf(var + 1e-5f);
    const float z   = (xv - m) * rs * lns + lnb;
    #pragma unroll
    for (int g = 0; g < GQ; ++g) {
      const float t = (z - (-2.f + (float)g*(4.f/3.f))) * 0.75f;
      cb[nn][tid*GQ + g] = __expf(-t*t);
    }
    cb[nn][KSPL + tid] = fsilu(xv);
    __syncthreads();   // protects wred reuse + publishes cb
  }

  const float4* __restrict__ w4 = reinterpret_cast<const float4*>(sW + (size_t)tid*KSPL);
  const float4* __restrict__ b4 = reinterpret_cast<const float4*>(bW + (size_t)tid*FEAT);
  const float4* __restrict__ c0 = reinterpret_cast<const float4*>(cb[0]);
  const float4* __restrict__ c1 = reinterpret_cast<const float4*>(cb[1]);
  const float4* __restrict__ c2 = reinterpret_cast<const float4*>(cb[2]);
  const float4* __restrict__ c3 = reinterpret_cast<const float4*>(cb[3]);

  const float bias = sb[tid] + bb[tid];
  float a0 = bias, a1 = bias, a2 = bias, a3 = bias;

  #pragma unroll 4
  for (int k = 0; k < KSPL/4; ++k) {
    const float4 w = w4[k];
    float4 c;
    c = c0[k]; a0 += w.x*c.x + w.y*c.y + w.z*c.z + w.w*c.w;
    c = c1[k]; a1 += w.x*c.x + w.y*c.y + w.z*c.z + w.w*c.w;
    c = c2[k]; a2 += w.x*c.x + w.y*c.y + w.z*c.z + w.w*c.w;
    c = c3[k]; a3 += w.x*c.x + w.y*c.y + w.z*c.z + w.w*c.w;
  }
  #pragma unroll 4
  for (int k = 0; k < FEAT/4; ++k) {
    const float4 w = b4[k];
    const int kk = KSPL/4 + k;
    float4 c;
    c = c0[kk]; a0 += w.x*c.x + w.y*c.y + w.z*c.z + w.w*c.w;
    c = c1[kk]; a1 += w.x*c.x + w.y*c.y + w.z*c.z + w.w*c.w;
    c = c2[kk]; a2 += w.x*c.x + w.y*c.y + w.z*c.z + w.w*c.w;
    c = c3[kk]; a3 += w.x*c.x + w.y*c.y + w.z*c.z + w.w*c.w;
  }
  (void)xv_keep;
  if (node0 + 0 < n_nodes) h[(size_t)(node0+0)*FEAT + tid] = a0;
  if (node0 + 1 < n_nodes) h[(size_t)(node0+1)*FEAT + tid] = a1;
  if (node0 + 2 < n_nodes) h[(size_t)(node0+2)*FEAT + tid] = a2;
  if (node0 + 3 < n_nodes) h[(size_t)(node0+3)*FEAT + tid] = a3;
}

// agg[i][f] = dinv[i]^2 * h[i][f]   (self-loop term; also fully initializes agg)
__global__ __launch_bounds__(256) void k_selfloop(const float* __restrict__ h,
                                                 const float* __restrict__ dinv,
                                                 float* __restrict__ agg, int n_elems){
  int i = blockIdx.x*256 + threadIdx.x;
  if (i >= n_elems) return;
  const int node = i >> 7;
  const float d = dinv[node];
  agg[i] = d*d*h[i];
}

// agg[dst] += dinv[src]*dinv[dst] * h[src]   — 2 edges per 256-thread block
__global__ __launch_bounds__(256) void k_edges(const float* __restrict__ h,
                                               const float* __restrict__ dinv,
                                               float* __restrict__ agg,
                                               const int* __restrict__ src,
                                               const int* __restrict__ dst, int ne){
  const int e = blockIdx.x*2 + (threadIdx.x >> 7);
  if (e >= ne) return;
  const int f = threadIdx.x & 127;
  const int s = src[e], d = dst[e];
  const float w = dinv[s]*dinv[d];
  atomicAdd(&agg[(size_t)d*FEAT + f], w * h[(size_t)s*FEAT + f]);
}

__global__ __launch_bounds__(256) void k_silu_bias(float* __restrict__ agg,
                                                   const float* __restrict__ b, int n_elems){
  int i = blockIdx.x*256 + threadIdx.x;
  if (i >= n_elems) return;
  agg[i] = fsilu(agg[i] + b[i & 127]);
}

// Pool: batch is sorted; chunk of 64 nodes per block, flush on segment change.
__global__ __launch_bounds__(128) void k_pool(const float* __restrict__ x,
                                              const int* __restrict__ batch,
                                              float* __restrict__ pooled,
                                              float* __restrict__ cnt, int n){
  const int f = threadIdx.x;
  const int start = blockIdx.x * 64;
  const int end   = min(start + 64, n);
  if (start >= end) return;
  int cur = batch[start];
  float acc = 0.f, c = 0.f;
  for (int i = start; i < end; ++i) {
    const int b = batch[i];
    if (b != cur) {
      atomicAdd(&pooled[(size_t)cur*FEAT + f], acc);
      if (f == 0) atomicAdd(&cnt[cur], c);
      cur = b; acc = 0.f; c = 0.f;
    }
    acc += x[(size_t)i*FEAT + f];
    c += 1.f;
  }
  atomicAdd(&pooled[(size_t)cur*FEAT + f], acc);
  if (f == 0) atomicAdd(&cnt[cur], c);
}

__global__ __launch_bounds__(128) void k_pool_div(float* __restrict__ pooled,
                                                  const float* __restrict__ cnt){
  const int g = blockIdx.x, f = threadIdx.x;
  pooled[(size_t)g*FEAT + f] /= fmaxf(cnt[g], 1.f);
}

// Readout FastKAN (128 -> 10) + log_softmax, one block per graph.
__global__ __launch_bounds__(128) void k_readout(const float* __restrict__ pooled,
    const float* __restrict__ ln_s, const float* __restrict__ ln_b,
    const float* __restrict__ sW, const float* __restrict__ sb,
    const float* __restrict__ bW, const float* __restrict__ bb,
    float* __restrict__ out){
  __shared__ float cb[KSPL + FEAT];
  __shared__ float wred[2][2];
  __shared__ float outv[NCLS];
  const int tid = threadIdx.x, lane = tid & 63, wave = tid >> 6;
  const int g = blockIdx.x;

  const float xv = pooled[(size_t)g*FEAT + tid];
  float s1 = xv, s2 = xv*xv;
  #pragma unroll
  for (int off = 32; off; off >>= 1) { s1 += __shfl_down(s1, off); s2 += __shfl_down(s2, off); }
  if (lane == 0) { wred[wave][0] = s1; wred[wave][1] = s2; }
  __syncthreads();
  const float m   = (wred[0][0] + wred[1][0]) * (1.f/FEAT);
  const float var = (wred[0][1] + wred[1][1]) * (1.f/FEAT) - m*m;
  const float rs  = rsqrtf(var + 1e-5f);
  const float z   = (xv - m) * rs * ln_s[tid] + ln_b[tid];
  #pragma unroll
  for (int gg = 0; gg < GQ; ++gg) {
    const float t = (z - (-2.f + (float)gg*(4.f/3.f))) * 0.75f;
    cb[tid*GQ + gg] = __expf(-t*t);
  }
  cb[KSPL + tid] = fsilu(xv);
  __syncthreads();

  if (tid < NCLS) {
    const float* wr = sW + (size_t)tid*KSPL;
    const float* br = bW + (size_t)tid*FEAT;
    float acc = sb[tid] + bb[tid];
    for (int k = 0; k < KSPL; ++k) acc += cb[k] * wr[k];
    for (int k = 0; k < FEAT; ++k) acc += cb[KSPL + k] * br[k];
    outv[tid] = acc;
  }
  __syncthreads();
  if (tid == 0) {
    float mx = -1e30f;
    for (int o = 0; o < NCLS; ++o) mx = fmaxf(mx, outv[o]);
    float se = 0.f;
    for (int o = 0; o < NCLS; ++o) se += __expf(outv[o] - mx);
    const float lse = mx + logf(se);
    for (int o = 0; o < NCLS; ++o) out[(size_t)g*NCLS + o] = outv[o] - lse;
  }
}

extern "C" void kernel_launch(void* const* d_in, const int* in_sizes, int n_in,
                              void* d_out, int out_size, void* d_ws, size_t ws_size,
                              hipStream_t stream) {
  const float* x     = (const float*)d_in[0];
  const int*   edge  = (const int*)d_in[1];     // [2][NE]: src then dst
  const int*   batch = (const int*)d_in[2];
  const float* ln_s  = (const float*)d_in[3];
  const float* ln_b  = (const float*)d_in[4];
  const float* sW    = (const float*)d_in[5];
  const float* sb    = (const float*)d_in[6];
  const float* bW    = (const float*)d_in[7];
  const float* bb    = (const float*)d_in[8];
  const float* gcn_b = (const float*)d_in[9];
  const float* ro_ln_s = (const float*)d_in[10];
  const float* ro_ln_b = (const float*)d_in[11];
  const float* ro_sW   = (const float*)d_in[12];
  const float* ro_sb   = (const float*)d_in[13];
  const float* ro_bW   = (const float*)d_in[14];
  const float* ro_bb   = (const float*)d_in[15];
  float* out = (float*)d_out;

  const int* src = edge;
  const int* dst = edge + NE;

  float* ws = (float*)d_ws;
  float* dinv   = ws;                        // NN
  float* bufA   = ws + 100000;               // NN*FEAT  (h)
  float* bufB   = bufA + (size_t)NN*FEAT;    // NN*FEAT  (agg / x_cur)
  float* pooled = bufB + (size_t)NN*FEAT;    // NGR*FEAT
  float* cnt    = pooled + NGR*FEAT;         // NGR

  const int NF = NN * FEAT;

  // degree -> dinv
  k_fill<<<(NN+255)/256, 256, 0, stream>>>(dinv, NN, 1.f);
  k_deg <<<(NE+255)/256, 256, 0, stream>>>(dst, dinv, NE);
  k_dinv<<<(NN+255)/256, 256, 0, stream>>>(dinv, NN);

  const float* xin = x;
  for (int l = 0; l < NL; ++l) {
    k_fkan<<<NN/4, 128, 0, stream>>>(xin, bufA,
        ln_s + l*FEAT, ln_b + l*FEAT,
        sW + (size_t)l*FEAT*KSPL, sb + l*FEAT,
        bW + (size_t)l*FEAT*FEAT, bb + l*FEAT, NN);
    k_selfloop<<<(NF+255)/256, 256, 0, stream>>>(bufA, dinv, bufB, NF);
    k_edges<<<NE/2, 256, 0, stream>>>(bufA, dinv, bufB, src, dst, NE);
    k_silu_bias<<<(NF+255)/256, 256, 0, stream>>>(bufB, gcn_b + l*FEAT, NF);
    xin = bufB;
  }

  k_fill<<<(NGR*FEAT + NGR + 255)/256, 256, 0, stream>>>(pooled, NGR*FEAT + NGR, 0.f);
  k_pool<<<(NN+63)/64, 128, 0, stream>>>(bufB, batch, pooled, cnt, NN);
  k_pool_div<<<NGR, 128, 0, stream>>>(pooled, cnt);
  k_readout<<<NGR, 128, 0, stream>>>(pooled, ro_ln_s, ro_ln_b,
                                     ro_sW, ro_sb, ro_bW, ro_bb, out);
}

// Round 2
// 1147.073 us; speedup vs baseline: 5.1909x; 5.1909x over previous
//
#include <hip/hip_runtime.h>
#include <math.h>

#define NN    100000
#define NE    1600000
#define FEAT  128
#define GQ    4
#define NL    3
#define NGR   64
#define NCLS  10
#define KSPL  512
#define NKS   10            /* K-steps of 64 (640 total) */
#define BM    64

typedef __attribute__((ext_vector_type(8))) short short8;
typedef __attribute__((ext_vector_type(4))) float floatx4;

__device__ __forceinline__ float fsilu(float x){ return x / (1.f + __expf(-x)); }
__device__ __forceinline__ ushort f2bf(float f){
  uint u = __builtin_bit_cast(uint, f);
  return (ushort)((u + 0x7FFFu + ((u >> 16) & 1u)) >> 16);
}
__device__ __forceinline__ float bf2f(ushort h){ return __builtin_bit_cast(float, ((uint)h) << 16); }

// ---------------- small utility kernels ----------------
__global__ __launch_bounds__(256) void k_zero_i(int* __restrict__ p, int n){
  int i = blockIdx.x*256 + threadIdx.x; if (i < n) p[i] = 0;
}
__global__ __launch_bounds__(256) void k_zero_f(float* __restrict__ p, int n){
  int i = blockIdx.x*256 + threadIdx.x; if (i < n) p[i] = 0.f;
}
__global__ __launch_bounds__(256) void k_hist(const int* __restrict__ dst, int* __restrict__ hist, int ne){
  int e = blockIdx.x*256 + threadIdx.x; if (e < ne) atomicAdd(&hist[dst[e]], 1);
}
__global__ __launch_bounds__(256) void k_dinv(const int* __restrict__ hist, float* __restrict__ dinv, int n){
  int i = blockIdx.x*256 + threadIdx.x; if (i < n) dinv[i] = rsqrtf((float)hist[i] + 1.f);
}

// single-block exclusive scan -> row_ptr + cursor copy
__global__ __launch_bounds__(1024) void k_scan(const int* __restrict__ hist,
                                               int* __restrict__ rp, int* __restrict__ cursor){
  __shared__ int lds[1024];
  const int tid = threadIdx.x;
  const int CH = (NN + 1023) / 1024;
  const int base = tid * CH;
  int sum = 0;
  for (int i = 0; i < CH; ++i){ int idx = base + i; if (idx < NN) sum += hist[idx]; }
  lds[tid] = sum; __syncthreads();
  for (int off = 1; off < 1024; off <<= 1){
    int v = (tid >= off) ? lds[tid - off] : 0;
    __syncthreads();
    lds[tid] += v;
    __syncthreads();
  }
  int run = lds[tid] - sum;
  for (int i = 0; i < CH; ++i){
    int idx = base + i;
    if (idx < NN){ rp[idx] = run; cursor[idx] = run; run += hist[idx]; }
  }
  if (tid == 1023) rp[NN] = lds[1023];
}

__global__ __launch_bounds__(256) void k_scatter(const int* __restrict__ src, const int* __restrict__ dst,
                                                 int* __restrict__ cursor, int* __restrict__ col, int ne){
  int e = blockIdx.x*256 + threadIdx.x;
  if (e >= ne) return;
  int d = dst[e];
  int pos = atomicAdd(&cursor[d], 1);
  col[pos] = src[e];
}

// weights -> bf16, concat [sW|bW] as W[n][k], pre-swizzled per 64-k tile image
__global__ __launch_bounds__(256) void k_wprep(const float* __restrict__ sW, const float* __restrict__ bW,
                                               ushort* __restrict__ wimg){
  int idx = blockIdx.x*256 + threadIdx.x;       // ((l*10+q)*128+n)*64+kk
  if (idx >= NL*NKS*128*64) return;
  int kk = idx & 63;
  int n  = (idx >> 6) & 127;
  int q  = (idx >> 13) % NKS;
  int l  = idx / (NKS*128*64);
  int kg = q*64 + kk;
  float v = (kg < KSPL) ? sW[((size_t)l*FEAT + n)*KSPL + kg]
                        : bW[((size_t)l*FEAT + n)*FEAT + (kg - KSPL)];
  size_t tile = ((size_t)l*NKS + q) * (128*64);
  uint byte_in_row = ((uint)(kk*2)) ^ (((uint)(n & 7)) << 4);
  wimg[tile + (size_t)n*64 + (byte_in_row >> 1)] = f2bf(v);
}

// ---------------- FKAN transform: fused LN + RBF + MFMA GEMM ----------------
// out: hprime[node][f] = dinv[node] * (basis@sW^T + silu(x)@bW^T + sb + bb)   (bf16)
template <typename TIn>
__global__ __launch_bounds__(256) void k_fkan(
    const TIn* __restrict__ xin,            // [NN][128] fp32 or bf16(ushort)
    const ushort* __restrict__ wimg,        // this layer's pre-swizzled image (10*8192 ushorts)
    const float* __restrict__ ln_s, const float* __restrict__ ln_b,
    const float* __restrict__ sb, const float* __restrict__ bb,
    const float* __restrict__ dinv,
    ushort* __restrict__ hprime)
{
  __shared__ char zb[64*256];        // z bf16 [64][128], xor-swizzled rows
  __shared__ char sA[2*8192];        // silu(x) A-tiles for q=8,9  [64][64] bf16 swizzled
  __shared__ char At[8192];          // basis A-tile [64][64] bf16 swizzled
  __shared__ char Bt[16384];         // B tile [128 n][64 k] bf16 swizzled
  __shared__ float lnS[128], lnB[128], sbias[128];

  const int tid  = threadIdx.x;
  const int lane = tid & 63, wv = tid >> 6;
  const int node0 = blockIdx.x * BM;

  if (tid < 128){ lnS[tid] = ln_s[tid]; lnB[tid] = ln_b[tid]; sbias[tid] = sb[tid] + bb[tid]; }

  // ---- layernorm phase: 4 threads per node ----
  const int lm = tid >> 2, part = tid & 3;
  const int node = node0 + lm;
  float xv[32];
  if (node < NN){
    if constexpr (sizeof(TIn) == 4){
      const float4* xr = (const float4*)((const float*)xin + (size_t)node*FEAT + part*32);
      #pragma unroll
      for (int j = 0; j < 8; ++j){ float4 v = xr[j]; xv[4*j]=v.x; xv[4*j+1]=v.y; xv[4*j+2]=v.z; xv[4*j+3]=v.w; }
    } else {
      const uint4* xr = (const uint4*)((const ushort*)xin + (size_t)node*FEAT + part*32);
      #pragma unroll
      for (int j = 0; j < 4; ++j){
        uint4 v = xr[j];
        uint w0=v.x, w1=v.y, w2=v.z, w3=v.w;
        xv[8*j+0]=bf2f((ushort)(w0&0xffff)); xv[8*j+1]=bf2f((ushort)(w0>>16));
        xv[8*j+2]=bf2f((ushort)(w1&0xffff)); xv[8*j+3]=bf2f((ushort)(w1>>16));
        xv[8*j+4]=bf2f((ushort)(w2&0xffff)); xv[8*j+5]=bf2f((ushort)(w2>>16));
        xv[8*j+6]=bf2f((ushort)(w3&0xffff)); xv[8*j+7]=bf2f((ushort)(w3>>16));
      }
    }
  } else {
    #pragma unroll
    for (int j = 0; j < 32; ++j) xv[j] = 0.f;
  }
  float s1 = 0.f, s2 = 0.f;
  #pragma unroll
  for (int j = 0; j < 32; ++j){ s1 += xv[j]; s2 += xv[j]*xv[j]; }
  s1 += __shfl_xor(s1, 1); s2 += __shfl_xor(s2, 1);
  s1 += __shfl_xor(s1, 2); s2 += __shfl_xor(s2, 2);
  const float mean = s1 * (1.f/128.f);
  const float var  = s2 * (1.f/128.f) - mean*mean;
  const float rs   = rsqrtf(var + 1e-5f);
  __syncthreads();                       // lnS/lnB staged
  {
    const uint swl = ((uint)(lm & 7)) << 4;
    #pragma unroll
    for (int j = 0; j < 32; j += 2){
      const int f = part*32 + j;
      float z0 = (xv[j]   - mean)*rs*lnS[f]   + lnB[f];
      float z1 = (xv[j+1] - mean)*rs*lnS[f+1] + lnB[f+1];
      *(uint*)(zb + lm*256 + (((uint)(f*2)) ^ swl)) = (uint)f2bf(z0) | ((uint)f2bf(z1) << 16);
      float u0 = fsilu(xv[j]), u1 = fsilu(xv[j+1]);
      const int qp = f >> 6, kk = f & 63;
      *(uint*)(sA + qp*8192 + lm*128 + (((uint)(kk*2)) ^ swl)) = (uint)f2bf(u0) | ((uint)f2bf(u1) << 16);
    }
  }
  __syncthreads();                       // zb, sA ready

  // ---- MFMA K-loop ----
  const int l15 = lane & 15, l4h = lane >> 4;
  const int wm = wv >> 1, wn = wv & 1;
  floatx4 acc[2][4];
  #pragma unroll
  for (int mr = 0; mr < 2; ++mr)
    #pragma unroll
    for (int nr = 0; nr < 4; ++nr){ floatx4 z4 = {0.f,0.f,0.f,0.f}; acc[mr][nr] = z4; }

  int rowA[2]; uint swA[2];
  #pragma unroll
  for (int mr = 0; mr < 2; ++mr){ rowA[mr] = wm*32 + mr*16 + l15; swA[mr] = ((uint)(rowA[mr] & 7)) << 4; }
  int colB[4]; uint swB[4];
  #pragma unroll
  for (int nr = 0; nr < 4; ++nr){ colB[nr] = wn*64 + nr*16 + l15; swB[nr] = ((uint)(colB[nr] & 7)) << 4; }

  for (int q = 0; q < NKS; ++q){
    // stage B tile (linear copy of pre-swizzled image)
    {
      const short8* gs = (const short8*)(wimg + (size_t)q*8192);
      short8* lsd = (short8*)Bt;
      lsd[tid      ] = gs[tid      ];
      lsd[tid + 256] = gs[tid + 256];
      lsd[tid + 512] = gs[tid + 512];
      lsd[tid + 768] = gs[tid + 768];
    }
    const char* Ab;
    if (q < 8){
      // generate basis A-tile: thread -> row (tid&63), 16 k's starting at (tid>>6)*16
      const int am = tid & 63, aw = tid >> 6;
      const uint sws = ((uint)(am & 7)) << 4;
      const int f0 = q*16 + aw*4;
      uint2 zz = *(const uint2*)(zb + am*256 + (((uint)(f0*2)) ^ sws));
      float zf[4];
      zf[0] = bf2f((ushort)(zz.x & 0xffff)); zf[1] = bf2f((ushort)(zz.x >> 16));
      zf[2] = bf2f((ushort)(zz.y & 0xffff)); zf[3] = bf2f((ushort)(zz.y >> 16));
      ushort e[16];
      #pragma unroll
      for (int fi = 0; fi < 4; ++fi)
        #pragma unroll
        for (int g = 0; g < 4; ++g){
          float t = (zf[fi] - (-2.f + (4.f/3.f)*(float)g)) * 0.75f;
          e[fi*4+g] = f2bf(__expf(-t*t));
        }
      short8 p0, p1;
      #pragma unroll
      for (int i = 0; i < 8; ++i){ p0[i] = (short)e[i]; p1[i] = (short)e[8+i]; }
      *(short8*)(At + am*128 + (((uint)(aw*32))      ^ sws)) = p0;
      *(short8*)(At + am*128 + (((uint)(aw*32 + 16)) ^ sws)) = p1;
      Ab = At;
    } else {
      Ab = sA + (q - 8)*8192;
    }
    __syncthreads();
    #pragma unroll
    for (int ks = 0; ks < 2; ++ks){
      const uint kb = (uint)(ks*64 + l4h*16);
      short8 af[2], bfr[4];
      #pragma unroll
      for (int mr = 0; mr < 2; ++mr)
        af[mr] = *(const short8*)(Ab + rowA[mr]*128 + (kb ^ swA[mr]));
      #pragma unroll
      for (int nr = 0; nr < 4; ++nr)
        bfr[nr] = *(const short8*)(Bt + colB[nr]*128 + (kb ^ swB[nr]));
      #pragma unroll
      for (int mr = 0; mr < 2; ++mr)
        #pragma unroll
        for (int nr = 0; nr < 4; ++nr)
          acc[mr][nr] = __builtin_amdgcn_mfma_f32_16x16x32_bf16(af[mr], bfr[nr], acc[mr][nr], 0, 0, 0);
    }
    __syncthreads();
  }

  // ---- epilogue: h' = dinv * (acc + bias), bf16 store ----
  #pragma unroll
  for (int mr = 0; mr < 2; ++mr){
    const int rbase = node0 + wm*32 + mr*16 + l4h*4;
    float dvv[4];
    #pragma unroll
    for (int j = 0; j < 4; ++j) dvv[j] = (rbase + j < NN) ? dinv[rbase + j] : 0.f;
    #pragma unroll
    for (int nr = 0; nr < 4; ++nr){
      const int cf = wn*64 + nr*16 + l15;
      const float sv = sbias[cf];
      #pragma unroll
      for (int j = 0; j < 4; ++j){
        const int r = rbase + j;
        if (r < NN) hprime[(size_t)r*FEAT + cf] = f2bf(dvv[j]*(acc[mr][nr][j] + sv));
      }
    }
  }
}

// ---------------- CSR aggregation + silu + bias (one wave per dst node) ----------------
__global__ __launch_bounds__(256) void k_agg(
    const ushort* __restrict__ hprime, const int* __restrict__ rp,
    const int* __restrict__ col, const float* __restrict__ dinv,
    const float* __restrict__ gb, ushort* __restrict__ xout)
{
  const int wv = threadIdx.x >> 6, lane = threadIdx.x & 63;
  const int d = blockIdx.x*4 + wv;
  const uint* h2 = (const uint*)hprime;
  uint v = h2[(size_t)d*64 + lane];
  float a0 = bf2f((ushort)(v & 0xffff)), a1 = bf2f((ushort)(v >> 16));
  const int j0 = rp[d], j1 = rp[d+1];
  for (int j = j0; j < j1; ++j){
    int s = col[j];
    uint w = h2[(size_t)s*64 + lane];
    a0 += bf2f((ushort)(w & 0xffff)); a1 += bf2f((ushort)(w >> 16));
  }
  const float dv = dinv[d];
  const float2 b2 = *(const float2*)(gb + 2*lane);
  a0 = fsilu(dv*a0 + b2.x);
  a1 = fsilu(dv*a1 + b2.y);
  ((uint*)xout)[(size_t)d*64 + lane] = (uint)f2bf(a0) | ((uint)f2bf(a1) << 16);
}

// ---------------- pooling (sorted batch) ----------------
__global__ __launch_bounds__(128) void k_pool(const ushort* __restrict__ x,
                                              const int* __restrict__ batch,
                                              float* __restrict__ pooled,
                                              float* __restrict__ cnt, int n){
  const int f = threadIdx.x;
  const int start = blockIdx.x * 64;
  const int end   = min(start + 64, n);
  if (start >= end) return;
  int cur = batch[start];
  float acc = 0.f, c = 0.f;
  for (int i = start; i < end; ++i){
    const int b = batch[i];
    if (b != cur){
      atomicAdd(&pooled[(size_t)cur*FEAT + f], acc);
      if (f == 0) atomicAdd(&cnt[cur], c);
      cur = b; acc = 0.f; c = 0.f;
    }
    acc += bf2f(x[(size_t)i*FEAT + f]);
    c += 1.f;
  }
  atomicAdd(&pooled[(size_t)cur*FEAT + f], acc);
  if (f == 0) atomicAdd(&cnt[cur], c);
}

__global__ __launch_bounds__(128) void k_pool_div(float* __restrict__ pooled,
                                                  const float* __restrict__ cnt){
  const int g = blockIdx.x, f = threadIdx.x;
  pooled[(size_t)g*FEAT + f] /= fmaxf(cnt[g], 1.f);
}

// ---------------- readout FastKAN (128 -> 10) + log_softmax ----------------
__global__ __launch_bounds__(128) void k_readout(const float* __restrict__ pooled,
    const float* __restrict__ ln_s, const float* __restrict__ ln_b,
    const float* __restrict__ sW, const float* __restrict__ sb,
    const float* __restrict__ bW, const float* __restrict__ bb,
    float* __restrict__ out){
  __shared__ float cb[KSPL + FEAT];
  __shared__ float wred[2][2];
  __shared__ float outv[NCLS];
  const int tid = threadIdx.x, lane = tid & 63, wave = tid >> 6;
  const int g = blockIdx.x;

  const float xvv = pooled[(size_t)g*FEAT + tid];
  float s1 = xvv, s2 = xvv*xvv;
  #pragma unroll
  for (int off = 32; off; off >>= 1){ s1 += __shfl_down(s1, off); s2 += __shfl_down(s2, off); }
  if (lane == 0){ wred[wave][0] = s1; wred[wave][1] = s2; }
  __syncthreads();
  const float m   = (wred[0][0] + wred[1][0]) * (1.f/FEAT);
  const float var = (wred[0][1] + wred[1][1]) * (1.f/FEAT) - m*m;
  const float rs  = rsqrtf(var + 1e-5f);
  const float z   = (xvv - m) * rs * ln_s[tid] + ln_b[tid];
  #pragma unroll
  for (int gg = 0; gg < GQ; ++gg){
    const float t = (z - (-2.f + (4.f/3.f)*(float)gg)) * 0.75f;
    cb[tid*GQ + gg] = __expf(-t*t);
  }
  cb[KSPL + tid] = fsilu(xvv);
  __syncthreads();

  if (tid < NCLS){
    const float* wr = sW + (size_t)tid*KSPL;
    const float* br = bW + (size_t)tid*FEAT;
    float acc = sb[tid] + bb[tid];
    for (int k = 0; k < KSPL; ++k) acc += cb[k] * wr[k];
    for (int k = 0; k < FEAT; ++k) acc += cb[KSPL + k] * br[k];
    outv[tid] = acc;
  }
  __syncthreads();
  if (tid == 0){
    float mx = -1e30f;
    for (int o = 0; o < NCLS; ++o) mx = fmaxf(mx, outv[o]);
    float se = 0.f;
    for (int o = 0; o < NCLS; ++o) se += __expf(outv[o] - mx);
    const float lse = mx + logf(se);
    for (int o = 0; o < NCLS; ++o) out[(size_t)g*NCLS + o] = outv[o] - lse;
  }
}

extern "C" void kernel_launch(void* const* d_in, const int* in_sizes, int n_in,
                              void* d_out, int out_size, void* d_ws, size_t ws_size,
                              hipStream_t stream) {
  const float* x     = (const float*)d_in[0];
  const int*   edge  = (const int*)d_in[1];
  const int*   batch = (const int*)d_in[2];
  const float* ln_s  = (const float*)d_in[3];
  const float* ln_b  = (const float*)d_in[4];
  const float* sW    = (const float*)d_in[5];
  const float* sb    = (const float*)d_in[6];
  const float* bW    = (const float*)d_in[7];
  const float* bb    = (const float*)d_in[8];
  const float* gcn_b = (const float*)d_in[9];
  const float* ro_ln_s = (const float*)d_in[10];
  const float* ro_ln_b = (const float*)d_in[11];
  const float* ro_sW   = (const float*)d_in[12];
  const float* ro_sb   = (const float*)d_in[13];
  const float* ro_bW   = (const float*)d_in[14];
  const float* ro_bb   = (const float*)d_in[15];
  float* out = (float*)d_out;

  const int* src = edge;
  const int* dst = edge + NE;

  char* W = (char*)d_ws;
  size_t off = 0;
  auto alloc = [&](size_t bytes){ size_t r = off; off += (bytes + 1023) & ~((size_t)1023); return r; };
  float*  dinv   = (float*) (W + alloc((size_t)NN*4));
  ushort* wimg   = (ushort*)(W + alloc((size_t)NL*NKS*8192*2));
  int*    hist   = (int*)   (W + alloc((size_t)NN*4));
  int*    rp     = (int*)   (W + alloc((size_t)(NN+1)*4));
  int*    cursor = (int*)   (W + alloc((size_t)NN*4));
  int*    col    = (int*)   (W + alloc((size_t)NE*4));
  ushort* hprime = (ushort*)(W + alloc((size_t)NN*FEAT*2));
  ushort* xcur   = (ushort*)(W + alloc((size_t)NN*FEAT*2));
  float*  pooled = (float*) (W + alloc((size_t)(NGR*FEAT + NGR)*4));
  float*  cnt    = pooled + NGR*FEAT;

  // CSR + degree norm (edge structure is layer-invariant)
  k_zero_i<<<(NN+255)/256, 256, 0, stream>>>(hist, NN);
  k_zero_f<<<(NGR*FEAT+NGR+255)/256, 256, 0, stream>>>(pooled, NGR*FEAT + NGR);
  k_hist<<<(NE+255)/256, 256, 0, stream>>>(dst, hist, NE);
  k_dinv<<<(NN+255)/256, 256, 0, stream>>>(hist, dinv, NN);
  k_scan<<<1, 1024, 0, stream>>>(hist, rp, cursor);
  k_scatter<<<(NE+255)/256, 256, 0, stream>>>(src, dst, cursor, col, NE);
  k_wprep<<<(NL*NKS*128*64 + 255)/256, 256, 0, stream>>>(sW, bW, wimg);

  const int fkan_grid = (NN + BM - 1) / BM;
  for (int l = 0; l < NL; ++l){
    const ushort* wl = wimg + (size_t)l*NKS*8192;
    if (l == 0)
      k_fkan<float><<<fkan_grid, 256, 0, stream>>>(x, wl,
          ln_s + l*FEAT, ln_b + l*FEAT, sb + l*FEAT, bb + l*FEAT, dinv, hprime);
    else
      k_fkan<ushort><<<fkan_grid, 256, 0, stream>>>(xcur, wl,
          ln_s + l*FEAT, ln_b + l*FEAT, sb + l*FEAT, bb + l*FEAT, dinv, hprime);
    k_agg<<<NN/4, 256, 0, stream>>>(hprime, rp, col, dinv, gcn_b + l*FEAT, xcur);
  }

  k_pool<<<(NN+63)/64, 128, 0, stream>>>(xcur, batch, pooled, cnt, NN);
  k_pool_div<<<NGR, 128, 0, stream>>>(pooled, cnt);
  k_readout<<<NGR, 128, 0, stream>>>(pooled, ro_ln_s, ro_ln_b,
                                     ro_sW, ro_sb, ro_bW, ro_bb, out);
}

// Round 3
// 677.213 us; speedup vs baseline: 8.7925x; 1.6938x over previous
//
#include <hip/hip_runtime.h>
#include <math.h>

#define NN    100000
#define NE    1600000
#define FEAT  128
#define GQ    4
#define NL    3
#define NGR   64
#define NCLS  10
#define KSPL  512
#define NKS   10            /* K-steps of 64 (640 total) */
#define BM    64
#define TILE  1024
#define NT    ((NN + TILE - 1) / TILE)   /* 98 scan tiles */

typedef __attribute__((ext_vector_type(8))) short short8;
typedef __attribute__((ext_vector_type(4))) float floatx4;

__device__ __forceinline__ float fsilu(float x){ return x / (1.f + __expf(-x)); }
__device__ __forceinline__ ushort f2bf(float f){
  uint u = __builtin_bit_cast(uint, f);
  return (ushort)((u + 0x7FFFu + ((u >> 16) & 1u)) >> 16);
}
__device__ __forceinline__ float bf2f(ushort h){ return __builtin_bit_cast(float, ((uint)h) << 16); }

// ---------------- small utility kernels ----------------
__global__ __launch_bounds__(256) void k_zero_i(int* __restrict__ p, int n){
  int i = blockIdx.x*256 + threadIdx.x; if (i < n) p[i] = 0;
}
__global__ __launch_bounds__(256) void k_zero_f(float* __restrict__ p, int n){
  int i = blockIdx.x*256 + threadIdx.x; if (i < n) p[i] = 0.f;
}
__global__ __launch_bounds__(256) void k_hist(const int* __restrict__ dst, int* __restrict__ hist, int ne){
  int e = blockIdx.x*256 + threadIdx.x; if (e < ne) atomicAdd(&hist[dst[e]], 1);
}

// ---- hierarchical exclusive scan over hist[NN] ----
__global__ __launch_bounds__(256) void k_scan_a(const int* __restrict__ hist, int* __restrict__ tsum){
  __shared__ int red[4];
  const int base = blockIdx.x * TILE;
  int s = 0;
  #pragma unroll
  for (int j = 0; j < 4; ++j){
    int idx = base + threadIdx.x + j*256;
    if (idx < NN) s += hist[idx];
  }
  #pragma unroll
  for (int off = 32; off; off >>= 1) s += __shfl_down(s, off);
  if ((threadIdx.x & 63) == 0) red[threadIdx.x >> 6] = s;
  __syncthreads();
  if (threadIdx.x == 0) tsum[blockIdx.x] = red[0] + red[1] + red[2] + red[3];
}

__global__ __launch_bounds__(128) void k_scan_b(const int* __restrict__ tsum,
                                                int* __restrict__ toff, int* __restrict__ rpN){
  __shared__ int lds[128];
  const int tid = threadIdx.x;
  int v = (tid < NT) ? tsum[tid] : 0;
  lds[tid] = v; __syncthreads();
  for (int off = 1; off < 128; off <<= 1){
    int u = (tid >= off) ? lds[tid - off] : 0;
    __syncthreads();
    lds[tid] += u;
    __syncthreads();
  }
  if (tid < NT) toff[tid] = lds[tid] - v;
  if (tid == NT - 1) *rpN = lds[tid];
}

__global__ __launch_bounds__(256) void k_scan_c(const int* __restrict__ hist,
                                                const int* __restrict__ toff,
                                                int* __restrict__ rp, int* __restrict__ cursor,
                                                float* __restrict__ dinv){
  __shared__ int lds[256];
  const int tid = threadIdx.x;
  const int base = blockIdx.x * TILE + tid*4;
  int h[4]; int s = 0;
  #pragma unroll
  for (int j = 0; j < 4; ++j){ int idx = base + j; h[j] = (idx < NN) ? hist[idx] : 0; s += h[j]; }
  lds[tid] = s; __syncthreads();
  for (int off = 1; off < 256; off <<= 1){
    int u = (tid >= off) ? lds[tid - off] : 0;
    __syncthreads();
    lds[tid] += u;
    __syncthreads();
  }
  int run = toff[blockIdx.x] + lds[tid] - s;
  #pragma unroll
  for (int j = 0; j < 4; ++j){
    int idx = base + j;
    if (idx < NN){
      rp[idx] = run; cursor[idx] = run; run += h[j];
      dinv[idx] = rsqrtf((float)h[j] + 1.f);
    }
  }
}

__global__ __launch_bounds__(256) void k_scatter(const int* __restrict__ src, const int* __restrict__ dst,
                                                 int* __restrict__ cursor, int* __restrict__ col, int ne){
  int e = blockIdx.x*256 + threadIdx.x;
  if (e >= ne) return;
  int d = dst[e];
  int pos = atomicAdd(&cursor[d], 1);
  col[pos] = src[e];
}

// weights -> bf16, concat [sW|bW] as W[n][k], pre-swizzled per 64-k tile image
__global__ __launch_bounds__(256) void k_wprep(const float* __restrict__ sW, const float* __restrict__ bW,
                                               ushort* __restrict__ wimg){
  int idx = blockIdx.x*256 + threadIdx.x;       // ((l*10+q)*128+n)*64+kk
  if (idx >= NL*NKS*128*64) return;
  int kk = idx & 63;
  int n  = (idx >> 6) & 127;
  int q  = (idx >> 13) % NKS;
  int l  = idx / (NKS*128*64);
  int kg = q*64 + kk;
  float v = (kg < KSPL) ? sW[((size_t)l*FEAT + n)*KSPL + kg]
                        : bW[((size_t)l*FEAT + n)*FEAT + (kg - KSPL)];
  size_t tile = ((size_t)l*NKS + q) * (128*64);
  uint byte_in_row = ((uint)(kk*2)) ^ (((uint)(n & 7)) << 4);
  wimg[tile + (size_t)n*64 + (byte_in_row >> 1)] = f2bf(v);
}

// ---------------- FKAN transform: fused LN + RBF + MFMA GEMM ----------------
template <typename TIn>
__global__ __launch_bounds__(256) void k_fkan(
    const TIn* __restrict__ xin,            // [NN][128] fp32 or bf16(ushort)
    const ushort* __restrict__ wimg,        // this layer's pre-swizzled image (10*8192 ushorts)
    const float* __restrict__ ln_s, const float* __restrict__ ln_b,
    const float* __restrict__ sb, const float* __restrict__ bb,
    const float* __restrict__ dinv,
    ushort* __restrict__ hprime)
{
  __shared__ char zb[64*256];        // z bf16 [64][128], xor-swizzled rows
  __shared__ char sA[2*8192];        // silu(x) A-tiles for q=8,9  [64][64] bf16 swizzled
  __shared__ char At[8192];          // basis A-tile [64][64] bf16 swizzled
  __shared__ char Bt[16384];         // B tile [128 n][64 k] bf16 swizzled
  __shared__ float lnS[128], lnB[128], sbias[128];

  const int tid  = threadIdx.x;
  const int lane = tid & 63, wv = tid >> 6;
  const int node0 = blockIdx.x * BM;

  if (tid < 128){ lnS[tid] = ln_s[tid]; lnB[tid] = ln_b[tid]; sbias[tid] = sb[tid] + bb[tid]; }

  // ---- layernorm phase: 4 threads per node ----
  const int lm = tid >> 2, part = tid & 3;
  const int node = node0 + lm;
  float xv[32];
  if (node < NN){
    if constexpr (sizeof(TIn) == 4){
      const float4* xr = (const float4*)((const float*)xin + (size_t)node*FEAT + part*32);
      #pragma unroll
      for (int j = 0; j < 8; ++j){ float4 v = xr[j]; xv[4*j]=v.x; xv[4*j+1]=v.y; xv[4*j+2]=v.z; xv[4*j+3]=v.w; }
    } else {
      const uint4* xr = (const uint4*)((const ushort*)xin + (size_t)node*FEAT + part*32);
      #pragma unroll
      for (int j = 0; j < 4; ++j){
        uint4 v = xr[j];
        uint w0=v.x, w1=v.y, w2=v.z, w3=v.w;
        xv[8*j+0]=bf2f((ushort)(w0&0xffff)); xv[8*j+1]=bf2f((ushort)(w0>>16));
        xv[8*j+2]=bf2f((ushort)(w1&0xffff)); xv[8*j+3]=bf2f((ushort)(w1>>16));
        xv[8*j+4]=bf2f((ushort)(w2&0xffff)); xv[8*j+5]=bf2f((ushort)(w2>>16));
        xv[8*j+6]=bf2f((ushort)(w3&0xffff)); xv[8*j+7]=bf2f((ushort)(w3>>16));
      }
    }
  } else {
    #pragma unroll
    for (int j = 0; j < 32; ++j) xv[j] = 0.f;
  }
  float s1 = 0.f, s2 = 0.f;
  #pragma unroll
  for (int j = 0; j < 32; ++j){ s1 += xv[j]; s2 += xv[j]*xv[j]; }
  s1 += __shfl_xor(s1, 1); s2 += __shfl_xor(s2, 1);
  s1 += __shfl_xor(s1, 2); s2 += __shfl_xor(s2, 2);
  const float mean = s1 * (1.f/128.f);
  const float var  = s2 * (1.f/128.f) - mean*mean;
  const float rs   = rsqrtf(var + 1e-5f);
  __syncthreads();                       // lnS/lnB staged
  {
    const uint swl = ((uint)(lm & 7)) << 4;
    #pragma unroll
    for (int j = 0; j < 32; j += 2){
      const int f = part*32 + j;
      float z0 = (xv[j]   - mean)*rs*lnS[f]   + lnB[f];
      float z1 = (xv[j+1] - mean)*rs*lnS[f+1] + lnB[f+1];
      *(uint*)(zb + lm*256 + (((uint)(f*2)) ^ swl)) = (uint)f2bf(z0) | ((uint)f2bf(z1) << 16);
      float u0 = fsilu(xv[j]), u1 = fsilu(xv[j+1]);
      const int qp = f >> 6, kk = f & 63;
      *(uint*)(sA + qp*8192 + lm*128 + (((uint)(kk*2)) ^ swl)) = (uint)f2bf(u0) | ((uint)f2bf(u1) << 16);
    }
  }
  __syncthreads();                       // zb, sA ready

  // ---- MFMA K-loop ----
  const int l15 = lane & 15, l4h = lane >> 4;
  const int wm = wv >> 1, wn = wv & 1;
  floatx4 acc[2][4];
  #pragma unroll
  for (int mr = 0; mr < 2; ++mr)
    #pragma unroll
    for (int nr = 0; nr < 4; ++nr){ floatx4 z4 = {0.f,0.f,0.f,0.f}; acc[mr][nr] = z4; }

  int rowA[2]; uint swA[2];
  #pragma unroll
  for (int mr = 0; mr < 2; ++mr){ rowA[mr] = wm*32 + mr*16 + l15; swA[mr] = ((uint)(rowA[mr] & 7)) << 4; }
  int colB[4]; uint swB[4];
  #pragma unroll
  for (int nr = 0; nr < 4; ++nr){ colB[nr] = wn*64 + nr*16 + l15; swB[nr] = ((uint)(colB[nr] & 7)) << 4; }

  for (int q = 0; q < NKS; ++q){
    // stage B tile (linear copy of pre-swizzled image)
    {
      const short8* gs = (const short8*)(wimg + (size_t)q*8192);
      short8* lsd = (short8*)Bt;
      lsd[tid      ] = gs[tid      ];
      lsd[tid + 256] = gs[tid + 256];
      lsd[tid + 512] = gs[tid + 512];
      lsd[tid + 768] = gs[tid + 768];
    }
    const char* Ab;
    if (q < 8){
      // generate basis A-tile: thread -> row (tid&63), 16 k's starting at (tid>>6)*16
      const int am = tid & 63, aw = tid >> 6;
      const uint sws = ((uint)(am & 7)) << 4;
      const int f0 = q*16 + aw*4;
      uint2 zz = *(const uint2*)(zb + am*256 + (((uint)(f0*2)) ^ sws));
      float zf[4];
      zf[0] = bf2f((ushort)(zz.x & 0xffff)); zf[1] = bf2f((ushort)(zz.x >> 16));
      zf[2] = bf2f((ushort)(zz.y & 0xffff)); zf[3] = bf2f((ushort)(zz.y >> 16));
      ushort e[16];
      #pragma unroll
      for (int fi = 0; fi < 4; ++fi)
        #pragma unroll
        for (int g = 0; g < 4; ++g){
          float t = (zf[fi] - (-2.f + (4.f/3.f)*(float)g)) * 0.75f;
          e[fi*4+g] = f2bf(__expf(-t*t));
        }
      short8 p0, p1;
      #pragma unroll
      for (int i = 0; i < 8; ++i){ p0[i] = (short)e[i]; p1[i] = (short)e[8+i]; }
      *(short8*)(At + am*128 + (((uint)(aw*32))      ^ sws)) = p0;
      *(short8*)(At + am*128 + (((uint)(aw*32 + 16)) ^ sws)) = p1;
      Ab = At;
    } else {
      Ab = sA + (q - 8)*8192;
    }
    __syncthreads();
    #pragma unroll
    for (int ks = 0; ks < 2; ++ks){
      const uint kb = (uint)(ks*64 + l4h*16);
      short8 af[2], bfr[4];
      #pragma unroll
      for (int mr = 0; mr < 2; ++mr)
        af[mr] = *(const short8*)(Ab + rowA[mr]*128 + (kb ^ swA[mr]));
      #pragma unroll
      for (int nr = 0; nr < 4; ++nr)
        bfr[nr] = *(const short8*)(Bt + colB[nr]*128 + (kb ^ swB[nr]));
      #pragma unroll
      for (int mr = 0; mr < 2; ++mr)
        #pragma unroll
        for (int nr = 0; nr < 4; ++nr)
          acc[mr][nr] = __builtin_amdgcn_mfma_f32_16x16x32_bf16(af[mr], bfr[nr], acc[mr][nr], 0, 0, 0);
    }
    __syncthreads();
  }

  // ---- epilogue: h' = dinv * (acc + bias), bf16 store ----
  #pragma unroll
  for (int mr = 0; mr < 2; ++mr){
    const int rbase = node0 + wm*32 + mr*16 + l4h*4;
    float dvv[4];
    #pragma unroll
    for (int j = 0; j < 4; ++j) dvv[j] = (rbase + j < NN) ? dinv[rbase + j] : 0.f;
    #pragma unroll
    for (int nr = 0; nr < 4; ++nr){
      const int cf = wn*64 + nr*16 + l15;
      const float sv = sbias[cf];
      #pragma unroll
      for (int j = 0; j < 4; ++j){
        const int r = rbase + j;
        if (r < NN) hprime[(size_t)r*FEAT + cf] = f2bf(dvv[j]*(acc[mr][nr][j] + sv));
      }
    }
  }
}

// ---------------- CSR aggregation + silu + bias (one wave per dst node) ----------------
__global__ __launch_bounds__(256) void k_agg(
    const ushort* __restrict__ hprime, const int* __restrict__ rp,
    const int* __restrict__ col, const float* __restrict__ dinv,
    const float* __restrict__ gb, ushort* __restrict__ xout)
{
  const int wv = threadIdx.x >> 6, lane = threadIdx.x & 63;
  const int d = blockIdx.x*4 + wv;
  const uint* h2 = (const uint*)hprime;
  uint v = h2[(size_t)d*64 + lane];
  float a0 = bf2f((ushort)(v & 0xffff)), a1 = bf2f((ushort)(v >> 16));
  const int j0 = rp[d], j1 = rp[d+1];
  int j = j0;
  for (; j + 3 < j1; j += 4){
    const int s0 = col[j], s1c = col[j+1], s2c = col[j+2], s3c = col[j+3];
    const uint w0 = h2[(size_t)s0*64 + lane];
    const uint w1 = h2[(size_t)s1c*64 + lane];
    const uint w2 = h2[(size_t)s2c*64 + lane];
    const uint w3 = h2[(size_t)s3c*64 + lane];
    a0 += bf2f((ushort)(w0 & 0xffff)) + bf2f((ushort)(w1 & 0xffff))
        + bf2f((ushort)(w2 & 0xffff)) + bf2f((ushort)(w3 & 0xffff));
    a1 += bf2f((ushort)(w0 >> 16)) + bf2f((ushort)(w1 >> 16))
        + bf2f((ushort)(w2 >> 16)) + bf2f((ushort)(w3 >> 16));
  }
  for (; j < j1; ++j){
    const int s = col[j];
    const uint w = h2[(size_t)s*64 + lane];
    a0 += bf2f((ushort)(w & 0xffff)); a1 += bf2f((ushort)(w >> 16));
  }
  const float dv = dinv[d];
  const float2 b2 = *(const float2*)(gb + 2*lane);
  a0 = fsilu(dv*a0 + b2.x);
  a1 = fsilu(dv*a1 + b2.y);
  ((uint*)xout)[(size_t)d*64 + lane] = (uint)f2bf(a0) | ((uint)f2bf(a1) << 16);
}

// ---------------- pooling (sorted batch) ----------------
__global__ __launch_bounds__(128) void k_pool(const ushort* __restrict__ x,
                                              const int* __restrict__ batch,
                                              float* __restrict__ pooled,
                                              float* __restrict__ cnt, int n){
  const int f = threadIdx.x;
  const int start = blockIdx.x * 64;
  const int end   = min(start + 64, n);
  if (start >= end) return;
  int cur = batch[start];
  float acc = 0.f, c = 0.f;
  for (int i = start; i < end; ++i){
    const int b = batch[i];
    if (b != cur){
      atomicAdd(&pooled[(size_t)cur*FEAT + f], acc);
      if (f == 0) atomicAdd(&cnt[cur], c);
      cur = b; acc = 0.f; c = 0.f;
    }
    acc += bf2f(x[(size_t)i*FEAT + f]);
    c += 1.f;
  }
  atomicAdd(&pooled[(size_t)cur*FEAT + f], acc);
  if (f == 0) atomicAdd(&cnt[cur], c);
}

__global__ __launch_bounds__(128) void k_pool_div(float* __restrict__ pooled,
                                                  const float* __restrict__ cnt){
  const int g = blockIdx.x, f = threadIdx.x;
  pooled[(size_t)g*FEAT + f] /= fmaxf(cnt[g], 1.f);
}

// ---------------- readout FastKAN (128 -> 10) + log_softmax ----------------
__global__ __launch_bounds__(128) void k_readout(const float* __restrict__ pooled,
    const float* __restrict__ ln_s, const float* __restrict__ ln_b,
    const float* __restrict__ sW, const float* __restrict__ sb,
    const float* __restrict__ bW, const float* __restrict__ bb,
    float* __restrict__ out){
  __shared__ float cb[KSPL + FEAT];
  __shared__ float wred[2][2];
  __shared__ float outv[NCLS];
  const int tid = threadIdx.x, lane = tid & 63, wave = tid >> 6;
  const int g = blockIdx.x;

  const float xvv = pooled[(size_t)g*FEAT + tid];
  float s1 = xvv, s2 = xvv*xvv;
  #pragma unroll
  for (int off = 32; off; off >>= 1){ s1 += __shfl_down(s1, off); s2 += __shfl_down(s2, off); }
  if (lane == 0){ wred[wave][0] = s1; wred[wave][1] = s2; }
  __syncthreads();
  const float m   = (wred[0][0] + wred[1][0]) * (1.f/FEAT);
  const float var = (wred[0][1] + wred[1][1]) * (1.f/FEAT) - m*m;
  const float rs  = rsqrtf(var + 1e-5f);
  const float z   = (xvv - m) * rs * ln_s[tid] + ln_b[tid];
  #pragma unroll
  for (int gg = 0; gg < GQ; ++gg){
    const float t = (z - (-2.f + (4.f/3.f)*(float)gg)) * 0.75f;
    cb[tid*GQ + gg] = __expf(-t*t);
  }
  cb[KSPL + tid] = fsilu(xvv);
  __syncthreads();

  if (tid < NCLS){
    const float* wr = sW + (size_t)tid*KSPL;
    const float* br = bW + (size_t)tid*FEAT;
    float acc = sb[tid] + bb[tid];
    for (int k = 0; k < KSPL; ++k) acc += cb[k] * wr[k];
    for (int k = 0; k < FEAT; ++k) acc += cb[KSPL + k] * br[k];
    outv[tid] = acc;
  }
  __syncthreads();
  if (tid == 0){
    float mx = -1e30f;
    for (int o = 0; o < NCLS; ++o) mx = fmaxf(mx, outv[o]);
    float se = 0.f;
    for (int o = 0; o < NCLS; ++o) se += __expf(outv[o] - mx);
    const float lse = mx + logf(se);
    for (int o = 0; o < NCLS; ++o) out[(size_t)g*NCLS + o] = outv[o] - lse;
  }
}

extern "C" void kernel_launch(void* const* d_in, const int* in_sizes, int n_in,
                              void* d_out, int out_size, void* d_ws, size_t ws_size,
                              hipStream_t stream) {
  const float* x     = (const float*)d_in[0];
  const int*   edge  = (const int*)d_in[1];
  const int*   batch = (const int*)d_in[2];
  const float* ln_s  = (const float*)d_in[3];
  const float* ln_b  = (const float*)d_in[4];
  const float* sW    = (const float*)d_in[5];
  const float* sb    = (const float*)d_in[6];
  const float* bW    = (const float*)d_in[7];
  const float* bb    = (const float*)d_in[8];
  const float* gcn_b = (const float*)d_in[9];
  const float* ro_ln_s = (const float*)d_in[10];
  const float* ro_ln_b = (const float*)d_in[11];
  const float* ro_sW   = (const float*)d_in[12];
  const float* ro_sb   = (const float*)d_in[13];
  const float* ro_bW   = (const float*)d_in[14];
  const float* ro_bb   = (const float*)d_in[15];
  float* out = (float*)d_out;

  const int* src = edge;
  const int* dst = edge + NE;

  char* W = (char*)d_ws;
  size_t off = 0;
  auto alloc = [&](size_t bytes){ size_t r = off; off += (bytes + 1023) & ~((size_t)1023); return r; };
  float*  dinv   = (float*) (W + alloc((size_t)NN*4));
  ushort* wimg   = (ushort*)(W + alloc((size_t)NL*NKS*8192*2));
  int*    hist   = (int*)   (W + alloc((size_t)NN*4));
  int*    rp     = (int*)   (W + alloc((size_t)(NN+1)*4));
  int*    cursor = (int*)   (W + alloc((size_t)NN*4));
  int*    col    = (int*)   (W + alloc((size_t)NE*4));
  int*    tsum   = (int*)   (W + alloc((size_t)NT*4));
  int*    toff   = (int*)   (W + alloc((size_t)NT*4));
  ushort* hprime = (ushort*)(W + alloc((size_t)NN*FEAT*2));
  ushort* xcur   = (ushort*)(W + alloc((size_t)NN*FEAT*2));
  float*  pooled = (float*) (W + alloc((size_t)(NGR*FEAT + NGR)*4));
  float*  cnt    = pooled + NGR*FEAT;

  // CSR + degree norm (edge structure is layer-invariant)
  k_zero_i<<<(NN+255)/256, 256, 0, stream>>>(hist, NN);
  k_zero_f<<<(NGR*FEAT+NGR+255)/256, 256, 0, stream>>>(pooled, NGR*FEAT + NGR);
  k_hist<<<(NE+255)/256, 256, 0, stream>>>(dst, hist, NE);
  k_scan_a<<<NT, 256, 0, stream>>>(hist, tsum);
  k_scan_b<<<1, 128, 0, stream>>>(tsum, toff, rp + NN);
  k_scan_c<<<NT, 256, 0, stream>>>(hist, toff, rp, cursor, dinv);
  k_scatter<<<(NE+255)/256, 256, 0, stream>>>(src, dst, cursor, col, NE);
  k_wprep<<<(NL*NKS*128*64 + 255)/256, 256, 0, stream>>>(sW, bW, wimg);

  const int fkan_grid = (NN + BM - 1) / BM;
  for (int l = 0; l < NL; ++l){
    const ushort* wl = wimg + (size_t)l*NKS*8192;
    if (l == 0)
      k_fkan<float><<<fkan_grid, 256, 0, stream>>>(x, wl,
          ln_s + l*FEAT, ln_b + l*FEAT, sb + l*FEAT, bb + l*FEAT, dinv, hprime);
    else
      k_fkan<ushort><<<fkan_grid, 256, 0, stream>>>(xcur, wl,
          ln_s + l*FEAT, ln_b + l*FEAT, sb + l*FEAT, bb + l*FEAT, dinv, hprime);
    k_agg<<<NN/4, 256, 0, stream>>>(hprime, rp, col, dinv, gcn_b + l*FEAT, xcur);
  }

  k_pool<<<(NN+63)/64, 128, 0, stream>>>(xcur, batch, pooled, cnt, NN);
  k_pool_div<<<NGR, 128, 0, stream>>>(pooled, cnt);
  k_readout<<<NGR, 128, 0, stream>>>(pooled, ro_ln_s, ro_ln_b,
                                     ro_sW, ro_sb, ro_bW, ro_bb, out);
}